// Round 1
// baseline (5091.892 us; speedup 1.0000x reference)
//
#include <hip/hip_runtime.h>
#include <hip/hip_bf16.h>

// Problem constants
#define BB   4
#define CIN_ 64
#define RIN_ 6
#define CH_  5
#define HH   64
#define WW_  128
#define COUT_ 64
#define ROUT_ 6
#define KDIM 384            // CIN*RIN
#define MDIM 384            // COUT*ROUT
#define PH   66
#define PW   130
#define PSZ  (PH*PW)        // 8580

#define WEXP_ELEMS (KDIM*9*MDIM)        // 1,327,104
#define WEXP_BYTES (WEXP_ELEMS*2)       // 2,654,208 (bf16)
#define P_ELEMS    ((long)BB*CH_*KDIM*PSZ) // 65,894,400

// _IDX_K % 7 (t=2 and t=6 are masked anyway)
__device__ const int IDXK[6][9] = {
    {5,4,6,6,0,3,6,1,2},
    {4,3,6,5,0,2,6,6,1},
    {3,2,6,4,0,1,6,5,6},
    {2,1,6,3,0,6,6,4,5},
    {1,6,6,2,0,5,6,3,4},
    {6,5,6,1,0,4,6,2,3},
};

// -------- kernel 1: expand weight (COUT,CIN,RIN,7) -> Wexp bf16 [k=384][t=9][m=384]
__global__ void wexp_kernel(const float* __restrict__ w, __hip_bfloat16* __restrict__ Wexp) {
    int e = blockIdx.x * blockDim.x + threadIdx.x;
    if (e >= WEXP_ELEMS) return;
    int m = e % MDIM;
    int t = (e / MDIM) % 9;
    int k = e / (MDIM * 9);
    int co = m / 6, ro = m % 6, ci = k / 6, ri = k % 6;
    float v = 0.f;
    if (t != 2 && t != 6) {
        int rw = (ri - ro + 6) % 6;
        int s  = IDXK[ro][t];
        v = w[((co * CIN_ + ci) * RIN_ + rw) * 7 + s];
    }
    Wexp[e] = __float2bfloat16(v);
}

// -------- kernel 2: gather/pad masked x -> P bf16 [b][chart][k=ci*6+ri][66][130]
__global__ void pad_kernel(const float* __restrict__ x, __hip_bfloat16* __restrict__ P) {
    long e = (long)blockIdx.x * blockDim.x + threadIdx.x;
    if (e >= P_ELEMS) return;
    int xx = (int)(e % PW);
    int yy = (int)((e / PW) % PH);
    int k  = (int)((e / PSZ) % KDIM);
    int c  = (int)((e / ((long)PSZ * KDIM)) % CH_);
    int b  = (int)(e / ((long)PSZ * KDIM * CH_));
    int ci = k / RIN_, r = k % RIN_;
    int sr = r, sc = c, sy = 0, sx = 0;
    bool zi = false;
    if (yy >= 1 && yy <= 64 && xx >= 1 && xx <= 128) {
        sy = yy - 1; sx = xx - 1;                                  // interior
    } else if (xx == 129) {
        if (yy >= 2) { sr = (r + 5) % 6; sc = (c + 1) % 5; sy = 0; sx = 129 - yy; }
        else zi = true;                                            // (0,129),(1,129)
    } else if (yy == 0) {
        if (xx >= 1 && xx <= 64)        { sc = (c + 4) % 5; sy = 63; sx = 63 + xx; }
        else if (xx >= 65 && xx <= 128) { sr = (r + 1) % 6; sc = (c + 4) % 5; sy = 128 - xx; sx = 127; }
        else zi = true;                                            // (0,0)
    } else if (yy == 65) {
        if (xx >= 65 && xx <= 128)      { sc = (c + 1) % 5; sy = 0; sx = xx - 65; }
        else if (xx >= 2 && xx <= 64)   { sr = (r + 1) % 6; sc = (c + 1) % 5; sy = 65 - xx; sx = 0; }
        else zi = true;                                            // (65,0),(65,1)
    } else { // xx==0, yy in [1,64]
        sr = (r + 5) % 6; sc = (c + 4) % 5; sy = 63; sx = 64 - yy;
    }
    if (zi) { sr = 0; sc = 0; sy = 0; sx = 0; }                    // flat index 0 of (RIN,5,H,W)
    float v = x[((((long)b * CIN_ + ci) * RIN_ + sr) * CH_ + sc) * (HH * WW_) + sy * WW_ + sx];
    if ((sy == 0 && sx == 127) || (sy == 63 && sx == 0)) v = 0.f;  // VMASK pre-gather
    P[e] = __float2bfloat16(v);
}

// -------- kernel 3: direct conv, f32 accum
// block: 64 m-channels x (4 rows x 32 cols) spatial, fixed (b, chart)
#define BM 64
#define TY 4
#define TX 32
#define KC 8

__global__ __launch_bounds__(256) void conv_kernel(
        const __hip_bfloat16* __restrict__ P,
        const __hip_bfloat16* __restrict__ Wexp,
        const float* __restrict__ bias,
        float* __restrict__ out) {
    __shared__ float Ws[KC][9][BM];          // 18,432 B
    __shared__ float Ps[KC][TY + 2][TX + 2]; //  6,528 B

    int bid = blockIdx.x;
    int mt = bid % 6;
    int xt = (bid / 6) % 4;
    int yt = (bid / 24) % 16;
    int c  = (bid / 384) % 5;
    int b  = bid / 1920;

    int tid = threadIdx.x;
    int tn = tid & 31;   // column
    int tm = tid >> 5;   // m-group (8 m's each)
    int m0 = mt * BM;
    int y0 = yt * TY;    // output-row base == padded-window top row
    int x0 = xt * TX;    // output-col base == padded-window left col

    float acc[8][TY];
    #pragma unroll
    for (int j = 0; j < 8; j++)
        #pragma unroll
        for (int rr = 0; rr < TY; rr++) acc[j][rr] = 0.f;

    const __hip_bfloat16* Pbc = P + (long)(b * CH_ + c) * KDIM * PSZ;

    for (int k0 = 0; k0 < KDIM; k0 += KC) {
        // stage weights: KC*9*64 = 4608 elems (18/thread, coalesced in m)
        #pragma unroll
        for (int i = tid; i < KC * 9 * BM; i += 256) {
            int mm = i & 63;
            int t  = (i >> 6) % 9;
            int kk = i / (9 * BM);
            Ws[kk][t][mm] = __bfloat162float(
                Wexp[(long)(k0 + kk) * (9 * MDIM) + t * MDIM + m0 + mm]);
        }
        // stage input patch: KC*6*34 = 1632 elems
        for (int i = tid; i < KC * 6 * 34; i += 256) {
            int col = i % 34;
            int row = (i / 34) % 6;
            int kk  = i / (6 * 34);
            Ps[kk][row][col] = __bfloat162float(
                Pbc[(long)(k0 + kk) * PSZ + (y0 + row) * PW + (x0 + col)]);
        }
        __syncthreads();

        #pragma unroll
        for (int kk = 0; kk < KC; kk++) {
            float p[6][3];
            #pragma unroll
            for (int rr = 0; rr < 6; rr++)
                #pragma unroll
                for (int dd = 0; dd < 3; dd++)
                    p[rr][dd] = Ps[kk][rr][tn + dd];
            #pragma unroll
            for (int t = 0; t < 9; t++) {
                if (t == 2 || t == 6) continue;   // masked corners
                const int dy = t / 3, dx = t % 3;
                float w[8];
                #pragma unroll
                for (int j = 0; j < 8; j++) w[j] = Ws[kk][t][tm * 8 + j];
                #pragma unroll
                for (int j = 0; j < 8; j++)
                    #pragma unroll
                    for (int rr = 0; rr < TY; rr++)
                        acc[j][rr] += w[j] * p[rr + dy][dx];
            }
        }
        __syncthreads();
    }

    // epilogue: bias + VMASK + store
    #pragma unroll
    for (int j = 0; j < 8; j++) {
        int m = m0 + tm * 8 + j;
        float bv = bias[m / 6];
        #pragma unroll
        for (int rr = 0; rr < TY; rr++) {
            int y = y0 + rr, xq = x0 + tn;
            float v = acc[j][rr] + bv;
            if ((y == 0 && xq == 127) || (y == 63 && xq == 0)) v = 0.f;
            out[((long)(b * MDIM + m) * CH_ + c) * (HH * WW_) + y * WW_ + xq] = v;
        }
    }
}

extern "C" void kernel_launch(void* const* d_in, const int* in_sizes, int n_in,
                              void* d_out, int out_size, void* d_ws, size_t ws_size,
                              hipStream_t stream) {
    const float* x    = (const float*)d_in[0];
    const float* w    = (const float*)d_in[1];
    const float* bias = (const float*)d_in[2];
    float* out        = (float*)d_out;

    __hip_bfloat16* Wexp = (__hip_bfloat16*)d_ws;
    __hip_bfloat16* P    = (__hip_bfloat16*)((char*)d_ws + WEXP_BYTES);

    wexp_kernel<<<(WEXP_ELEMS + 255) / 256, 256, 0, stream>>>(w, Wexp);
    pad_kernel<<<(int)((P_ELEMS + 255) / 256), 256, 0, stream>>>(x, P);

    // grid: 6 m-tiles * 4 x-tiles * 16 y-tiles * 5 charts * 4 batch = 7680 blocks
    conv_kernel<<<7680, 256, 0, stream>>>(P, Wexp, bias, out);
}

// Round 2
// 1321.758 us; speedup vs baseline: 3.8524x; 3.8524x over previous
//
#include <hip/hip_runtime.h>
#include <hip/hip_bf16.h>

// Problem constants
#define BB    4
#define CIN_  64
#define RIN_  6
#define CH_   5
#define HH    64
#define WW_   128
#define COUT_ 64
#define ROUT_ 6
#define KD    384           // CIN*RIN = MDIM too
#define MD    384
#define PH    66
#define PW    130
#define PSZ   (PH*PW)       // 8580

#define NTAP 7
#define WEXP2_ELEMS (NTAP*MD*KD)          // 1,032,192
#define WEXP2_BYTES (WEXP2_ELEMS*2)       // 2,064,384
#define NBORD 388                          // 2*130 + 2*64 border cells per chart

typedef __attribute__((ext_vector_type(8))) short bf16x8;
typedef __attribute__((ext_vector_type(4))) float f32x4;

// live taps of the 3x3 (corners (0,2),(2,0) masked): t in {0,1,3,4,5,7,8}
__device__ const int TMAP[NTAP] = {0,1,3,4,5,7,8};

// _IDX_K % 7
__device__ const int IDXK[6][9] = {
    {5,4,6,6,0,3,6,1,2},
    {4,3,6,5,0,2,6,6,1},
    {3,2,6,4,0,1,6,5,6},
    {2,1,6,3,0,6,6,4,5},
    {1,6,6,2,0,5,6,3,4},
    {6,5,6,1,0,4,6,2,3},
};

// -------- kernel 1: expand weight (COUT,CIN,RIN,7) -> W2 bf16 [tt=7][m=384][k=384]
__global__ void wexp2_kernel(const float* __restrict__ w, __hip_bfloat16* __restrict__ W2) {
    int e = blockIdx.x * blockDim.x + threadIdx.x;
    if (e >= WEXP2_ELEMS) return;
    int k  = e % KD;
    int m  = (e / KD) % MD;
    int tt = e / (KD * MD);
    int t  = TMAP[tt];
    int co = m / 6, ro = m % 6, ci = k / 6, ri = k % 6;
    int rw = (ri - ro + 6) % 6;
    int s  = IDXK[ro][t];
    W2[e] = __float2bfloat16(w[((co * CIN_ + ci) * RIN_ + rw) * 7 + s]);
}

// -------- kernel 2a: interior pad (transpose to channel-last), coalesced
// P layout: [b][c][yy=66][xx=130][k=384] bf16
__global__ __launch_bounds__(256) void pad_interior(const float* __restrict__ x,
                                                    __hip_bfloat16* __restrict__ P) {
    int bid  = blockIdx.x;
    int kblk = bid % 3;            // 3 * 128 k
    int xh   = (bid / 3) & 1;      // 2 * 64 x
    int y    = (bid / 6) % 64;     // source row
    int bc   = bid / 384;
    int c = bc % 5, b = bc / 5;

    int lane = threadIdx.x & 63;
    int wv   = threadIdx.x >> 6;   // 4 waves -> 4 * 32 k
    int k0   = kblk * 128 + wv * 32;
    int sx   = xh * 64 + lane;
    int xx   = sx + 1;

    bool mask0 = (y == 0 && sx == 127) || (y == 63 && sx == 0);   // VMASK

    // source addr is linear in k: (((b*384 + k)*5 + c)*64 + y)*128 + sx
    const float* src = x + ((((size_t)(b * 384 + k0) * 5 + c) * 64 + y) * 128 + sx);
    unsigned int hbuf[16];
    #pragma unroll
    for (int kk = 0; kk < 32; kk += 2) {
        float v1 = src[(size_t)kk * 40960];
        float v2 = src[(size_t)(kk + 1) * 40960];
        if (mask0) { v1 = 0.f; v2 = 0.f; }
        __hip_bfloat16 h1 = __float2bfloat16(v1);
        __hip_bfloat16 h2 = __float2bfloat16(v2);
        hbuf[kk >> 1] = ((unsigned int)*(unsigned short*)&h2 << 16) |
                        (unsigned int)*(unsigned short*)&h1;
    }
    __hip_bfloat16* dst = P + (((size_t)(b * 5 + c) * PH + (y + 1)) * PW + xx) * KD + k0;
    uint4* d4 = (uint4*)dst;
    #pragma unroll
    for (int q = 0; q < 4; ++q)
        d4[q] = make_uint4(hbuf[4*q], hbuf[4*q+1], hbuf[4*q+2], hbuf[4*q+3]);
}

// -------- kernel 2b: border gather (tiny), same logic as round-1 (verified)
__global__ void pad_border(const float* __restrict__ x, __hip_bfloat16* __restrict__ P) {
    int e = blockIdx.x * blockDim.x + threadIdx.x;
    if (e >= 20 * NBORD * KD) return;
    int k  = e % KD;
    int p  = (e / KD) % NBORD;
    int bc = e / (KD * NBORD);
    int c = bc % 5, b = bc / 5;
    int yy, xx;
    if (p < 130)      { yy = 0;  xx = p; }
    else if (p < 260) { yy = 65; xx = p - 130; }
    else if (p < 324) { yy = 1 + (p - 260); xx = 0; }
    else              { yy = 1 + (p - 324); xx = 129; }

    int ci = k / RIN_, r = k % RIN_;
    int sr = r, sc = c, sy = 0, sx = 0;
    bool zi = false;
    if (yy >= 1 && yy <= 64 && xx >= 1 && xx <= 128) {
        sy = yy - 1; sx = xx - 1;                 // unreachable for border p
    } else if (xx == 129) {
        if (yy >= 2) { sr = (r + 5) % 6; sc = (c + 1) % 5; sy = 0; sx = 129 - yy; }
        else zi = true;
    } else if (yy == 0) {
        if (xx >= 1 && xx <= 64)        { sc = (c + 4) % 5; sy = 63; sx = 63 + xx; }
        else if (xx >= 65 && xx <= 128) { sr = (r + 1) % 6; sc = (c + 4) % 5; sy = 128 - xx; sx = 127; }
        else zi = true;
    } else if (yy == 65) {
        if (xx >= 65 && xx <= 128)      { sc = (c + 1) % 5; sy = 0; sx = xx - 65; }
        else if (xx >= 2 && xx <= 64)   { sr = (r + 1) % 6; sc = (c + 1) % 5; sy = 65 - xx; sx = 0; }
        else zi = true;
    } else { // xx==0, yy in [1,64]
        sr = (r + 5) % 6; sc = (c + 4) % 5; sy = 63; sx = 64 - yy;
    }
    if (zi) { sr = 0; sc = 0; sy = 0; sx = 0; }
    float v = x[((((size_t)b * 384 + (ci * 6 + sr)) * 5 + sc) * 64 + sy) * 128 + sx];
    if ((sy == 0 && sx == 127) || (sy == 63 && sx == 0)) v = 0.f;
    P[(((size_t)(b * 5 + c) * PH + yy) * PW + xx) * KD + k] = __float2bfloat16(v);
}

// -------- kernel 3: implicit-GEMM conv via MFMA
// wave: 64 m x 64 x (one output row y); block: 4 waves = 128 m x 128 x
// grid: 3 m-blocks x 64 y x 20 (b,c)
__global__ __launch_bounds__(256) void conv_mfma(
        const __hip_bfloat16* __restrict__ P,
        const __hip_bfloat16* __restrict__ W2,
        const float* __restrict__ bias,
        float* __restrict__ out) {
    int bid  = blockIdx.x;
    int mblk = bid % 3;
    int y    = (bid / 3) % 64;
    int bc   = bid / 192;
    int c = bc % 5, b = bc / 5;

    int tid  = threadIdx.x;
    int lane = tid & 63;
    int wv   = tid >> 6;
    int wm   = wv >> 1, wn = wv & 1;
    int m0   = mblk * 128 + wm * 64;
    int x0   = wn * 64;

    int lm = lane & 15, lg = lane >> 4;

    const __hip_bfloat16* Abase = W2 + (size_t)(m0 + lm) * KD + 8 * lg;
    const __hip_bfloat16* Pbase = P + (((size_t)(b * 5 + c) * PH + y) * PW + x0 + lm) * KD + 8 * lg;

    f32x4 acc[4][4] = {};

    const int DY[NTAP] = {0,0,1,1,1,2,2};
    const int DX[NTAP] = {0,1,0,1,2,1,2};

    for (int k0 = 0; k0 < KD; k0 += 32) {
        #pragma unroll
        for (int tt = 0; tt < NTAP; ++tt) {
            const __hip_bfloat16* ap = Abase + (size_t)tt * (MD * KD) + k0;
            const __hip_bfloat16* bp = Pbase + (size_t)(DY[tt] * PW + DX[tt]) * KD + k0;
            bf16x8 a[4], bb[4];
            #pragma unroll
            for (int i = 0; i < 4; ++i)
                a[i] = *(const bf16x8*)(ap + (size_t)i * 16 * KD);
            #pragma unroll
            for (int j = 0; j < 4; ++j)
                bb[j] = *(const bf16x8*)(bp + (size_t)j * 16 * KD);
            #pragma unroll
            for (int i = 0; i < 4; ++i)
                #pragma unroll
                for (int j = 0; j < 4; ++j)
                    acc[i][j] = __builtin_amdgcn_mfma_f32_16x16x32_bf16(
                        a[i], bb[j], acc[i][j], 0, 0, 0);
        }
    }

    // epilogue: bias + VMASK + store
    #pragma unroll
    for (int i = 0; i < 4; ++i) {
        int mbase = m0 + i * 16 + lg * 4;
        #pragma unroll
        for (int r = 0; r < 4; ++r) {
            int m = mbase + r;
            float bv = bias[m / 6];
            #pragma unroll
            for (int j = 0; j < 4; ++j) {
                int xq = x0 + j * 16 + lm;
                float v = acc[i][j][r] + bv;
                if ((y == 0 && xq == 127) || (y == 63 && xq == 0)) v = 0.f;
                out[((size_t)(b * MD + m) * CH_ + c) * (HH * WW_) + y * WW_ + xq] = v;
            }
        }
    }
}

extern "C" void kernel_launch(void* const* d_in, const int* in_sizes, int n_in,
                              void* d_out, int out_size, void* d_ws, size_t ws_size,
                              hipStream_t stream) {
    const float* x    = (const float*)d_in[0];
    const float* w    = (const float*)d_in[1];
    const float* bias = (const float*)d_in[2];
    float* out        = (float*)d_out;

    __hip_bfloat16* W2 = (__hip_bfloat16*)d_ws;
    __hip_bfloat16* P  = (__hip_bfloat16*)((char*)d_ws + WEXP2_BYTES);

    wexp2_kernel<<<(WEXP2_ELEMS + 255) / 256, 256, 0, stream>>>(w, W2);
    pad_interior<<<20 * 64 * 2 * 3, 256, 0, stream>>>(x, P);
    pad_border<<<(20 * NBORD * KD + 255) / 256, 256, 0, stream>>>(x, P);
    conv_mfma<<<3 * 64 * 20, 256, 0, stream>>>(P, W2, bias, out);
}

// Round 3
// 604.815 us; speedup vs baseline: 8.4189x; 2.1854x over previous
//
#include <hip/hip_runtime.h>
#include <hip/hip_bf16.h>

// Problem constants
#define BB    4
#define CIN_  64
#define RIN_  6
#define CH_   5
#define HH    64
#define WW_   128
#define COUT_ 64
#define ROUT_ 6
#define KD    384
#define MD    384
#define PH    66
#define PW    130
#define PSZ   (PH*PW)

#define NTAP 7
#define WEXP2_ELEMS (NTAP*MD*KD)          // 1,032,192
#define WEXP2_BYTES (WEXP2_ELEMS*2)
#define NBORD 388
#define NCHUNK 84                          // 7 taps * 12 k-chunks of 32

typedef __attribute__((ext_vector_type(8))) short bf16x8;
typedef __attribute__((ext_vector_type(4))) float f32x4;

__device__ const int TMAP[NTAP] = {0,1,3,4,5,7,8};
__device__ const int IDXK[6][9] = {
    {5,4,6,6,0,3,6,1,2},
    {4,3,6,5,0,2,6,6,1},
    {3,2,6,4,0,1,6,5,6},
    {2,1,6,3,0,6,6,4,5},
    {1,6,6,2,0,5,6,3,4},
    {6,5,6,1,0,4,6,2,3},
};

// -------- kernel 1: expand weight -> W2 bf16 [tt=7][m=384][k=384]
__global__ void wexp2_kernel(const float* __restrict__ w, __hip_bfloat16* __restrict__ W2) {
    int e = blockIdx.x * blockDim.x + threadIdx.x;
    if (e >= WEXP2_ELEMS) return;
    int k  = e % KD;
    int m  = (e / KD) % MD;
    int tt = e / (KD * MD);
    int t  = TMAP[tt];
    int co = m / 6, ro = m % 6, ci = k / 6, ri = k % 6;
    int rw = (ri - ro + 6) % 6;
    int s  = IDXK[ro][t];
    W2[e] = __float2bfloat16(w[((co * CIN_ + ci) * RIN_ + rw) * 7 + s]);
}

// -------- kernel 2a: interior pad (transpose to channel-last)
// P layout: [b][c][yy=66][xx=130][k=384] bf16
__global__ __launch_bounds__(256) void pad_interior(const float* __restrict__ x,
                                                    __hip_bfloat16* __restrict__ P) {
    int bid  = blockIdx.x;
    int kblk = bid % 3;
    int xh   = (bid / 3) & 1;
    int y    = (bid / 6) % 64;
    int bc   = bid / 384;
    int c = bc % 5, b = bc / 5;

    int lane = threadIdx.x & 63;
    int wv   = threadIdx.x >> 6;
    int k0   = kblk * 128 + wv * 32;
    int sx   = xh * 64 + lane;
    int xx   = sx + 1;

    bool mask0 = (y == 0 && sx == 127) || (y == 63 && sx == 0);

    const float* src = x + ((((size_t)(b * 384 + k0) * 5 + c) * 64 + y) * 128 + sx);
    unsigned int hbuf[16];
    #pragma unroll
    for (int kk = 0; kk < 32; kk += 2) {
        float v1 = src[(size_t)kk * 40960];
        float v2 = src[(size_t)(kk + 1) * 40960];
        if (mask0) { v1 = 0.f; v2 = 0.f; }
        __hip_bfloat16 h1 = __float2bfloat16(v1);
        __hip_bfloat16 h2 = __float2bfloat16(v2);
        hbuf[kk >> 1] = ((unsigned int)*(unsigned short*)&h2 << 16) |
                        (unsigned int)*(unsigned short*)&h1;
    }
    __hip_bfloat16* dst = P + (((size_t)(b * 5 + c) * PH + (y + 1)) * PW + xx) * KD + k0;
    uint4* d4 = (uint4*)dst;
    #pragma unroll
    for (int q = 0; q < 4; ++q)
        d4[q] = make_uint4(hbuf[4*q], hbuf[4*q+1], hbuf[4*q+2], hbuf[4*q+3]);
}

// -------- kernel 2b: border gather
__global__ void pad_border(const float* __restrict__ x, __hip_bfloat16* __restrict__ P) {
    int e = blockIdx.x * blockDim.x + threadIdx.x;
    if (e >= 20 * NBORD * KD) return;
    int k  = e % KD;
    int p  = (e / KD) % NBORD;
    int bc = e / (KD * NBORD);
    int c = bc % 5, b = bc / 5;
    int yy, xx;
    if (p < 130)      { yy = 0;  xx = p; }
    else if (p < 260) { yy = 65; xx = p - 130; }
    else if (p < 324) { yy = 1 + (p - 260); xx = 0; }
    else              { yy = 1 + (p - 324); xx = 129; }

    int ci = k / RIN_, r = k % RIN_;
    int sr = r, sc = c, sy = 0, sx = 0;
    bool zi = false;
    if (xx == 129) {
        if (yy >= 2) { sr = (r + 5) % 6; sc = (c + 1) % 5; sy = 0; sx = 129 - yy; }
        else zi = true;
    } else if (yy == 0) {
        if (xx >= 1 && xx <= 64)        { sc = (c + 4) % 5; sy = 63; sx = 63 + xx; }
        else if (xx >= 65 && xx <= 128) { sr = (r + 1) % 6; sc = (c + 4) % 5; sy = 128 - xx; sx = 127; }
        else zi = true;
    } else if (yy == 65) {
        if (xx >= 65 && xx <= 128)      { sc = (c + 1) % 5; sy = 0; sx = xx - 65; }
        else if (xx >= 2 && xx <= 64)   { sr = (r + 1) % 6; sc = (c + 1) % 5; sy = 65 - xx; sx = 0; }
        else zi = true;
    } else { // xx==0, yy in [1,64]
        sr = (r + 5) % 6; sc = (c + 4) % 5; sy = 63; sx = 64 - yy;
    }
    if (zi) { sr = 0; sc = 0; sy = 0; sx = 0; }
    float v = x[((((size_t)b * 384 + (ci * 6 + sr)) * 5 + sc) * 64 + sy) * 128 + sx];
    if ((sy == 0 && sx == 127) || (sy == 63 && sx == 0)) v = 0.f;
    P[(((size_t)(b * 5 + c) * PH + yy) * PW + xx) * KD + k] = __float2bfloat16(v);
}

// -------- kernel 3: implicit-GEMM conv, m97 structure
// block: 128 m x 128 x (one output row y); 4 waves (2 wm x 2 wn), 64x64 each
// K loop: 84 chunks = 7 taps x 12 k-chunks of 32
// LDS: A/B double-buffered, 512 slots x 16 B each, XOR-swizzled (slot k8 ^= idx&3)
__global__ __launch_bounds__(256) void conv_mfma(
        const __hip_bfloat16* __restrict__ P,
        const __hip_bfloat16* __restrict__ W2,
        const float* __restrict__ bias,
        float* __restrict__ out) {
    __shared__ __hip_bfloat16 As[2][4096];   // 128 m  x 32 k
    __shared__ __hip_bfloat16 Bs[2][4096];   // 128 col x 32 k

    int bid = blockIdx.x;
    int w   = (bid & 7) * 480 + (bid >> 3);  // XCD-aware swizzle (3840 = 8*480)
    int mblk = w % 3;
    int y    = (w / 3) & 63;
    int bc   = w / 192;
    int c = bc % 5, b = bc / 5;

    int tid  = threadIdx.x;
    int lane = tid & 63;
    int wv   = tid >> 6;
    int wm   = wv >> 1, wn = wv & 1;
    int lm   = lane & 15, lg = lane >> 4;

    const __hip_bfloat16* Pslice = P + (size_t)(b * 5 + c) * PSZ * KD;
    const __hip_bfloat16* Wm     = W2 + (size_t)mblk * 128 * KD;

    const int DY[NTAP] = {0,0,1,1,1,2,2};
    const int DX[NTAP] = {0,1,0,1,2,1,2};

    // stage chunk ch into buffer buf: pre-swizzled source, linear LDS dest
    auto stage = [&](int buf, int ch) {
        int tt = ch / 12;
        int k0 = (ch % 12) * 32;
        int row = y + DY[tt];
        int dx  = DX[tt];
        #pragma unroll
        for (int q = 0; q < 2; ++q) {
            int s  = wv * 128 + q * 64 + lane;      // slot = mm*4 + k8
            int mm = s >> 2, k8 = s & 3;
            const __hip_bfloat16* g = Wm + ((size_t)tt * MD + mm) * KD + k0 + ((k8 ^ (mm & 3)) << 3);
            __builtin_amdgcn_global_load_lds(
                (const __attribute__((address_space(1))) void*)g,
                (__attribute__((address_space(3))) void*)&As[buf][(wv * 128 + q * 64) * 8],
                16, 0, 0);
        }
        #pragma unroll
        for (int q = 0; q < 2; ++q) {
            int s   = wv * 128 + q * 64 + lane;     // slot = col*4 + k8
            int col = s >> 2, k8 = s & 3;
            const __hip_bfloat16* g = Pslice + ((size_t)row * PW + dx + col) * KD + k0 + ((k8 ^ (col & 3)) << 3);
            __builtin_amdgcn_global_load_lds(
                (const __attribute__((address_space(1))) void*)g,
                (__attribute__((address_space(3))) void*)&Bs[buf][(wv * 128 + q * 64) * 8],
                16, 0, 0);
        }
    };

    f32x4 acc[4][4] = {};

    stage(0, 0);
    int cur = 0;
    for (int ch = 0; ch < NCHUNK; ++ch) {
        __syncthreads();                       // drains vmcnt: stage(ch) landed
        if (ch + 1 < NCHUNK) stage(cur ^ 1, ch + 1);   // prefetch next chunk

        bf16x8 a[4], bb[4];
        #pragma unroll
        for (int i = 0; i < 4; ++i) {
            int mm = wm * 64 + i * 16 + lm;
            a[i] = *(const bf16x8*)&As[cur][(mm * 4 + (lg ^ (mm & 3))) * 8];
        }
        #pragma unroll
        for (int j = 0; j < 4; ++j) {
            int col = wn * 64 + j * 16 + lm;
            bb[j] = *(const bf16x8*)&Bs[cur][(col * 4 + (lg ^ (col & 3))) * 8];
        }
        #pragma unroll
        for (int i = 0; i < 4; ++i)
            #pragma unroll
            for (int j = 0; j < 4; ++j)
                acc[i][j] = __builtin_amdgcn_mfma_f32_16x16x32_bf16(a[i], bb[j], acc[i][j], 0, 0, 0);
        cur ^= 1;
    }

    // epilogue: bias + VMASK + store
    int m0 = mblk * 128 + wm * 64;
    int x0 = wn * 64;
    #pragma unroll
    for (int i = 0; i < 4; ++i) {
        int mbase = m0 + i * 16 + lg * 4;
        #pragma unroll
        for (int r = 0; r < 4; ++r) {
            int m = mbase + r;
            float bv = bias[m / 6];
            #pragma unroll
            for (int j = 0; j < 4; ++j) {
                int xq = x0 + j * 16 + lm;
                float v = acc[i][j][r] + bv;
                if ((y == 0 && xq == 127) || (y == 63 && xq == 0)) v = 0.f;
                out[((size_t)(b * MD + m) * CH_ + c) * (HH * WW_) + y * WW_ + xq] = v;
            }
        }
    }
}

extern "C" void kernel_launch(void* const* d_in, const int* in_sizes, int n_in,
                              void* d_out, int out_size, void* d_ws, size_t ws_size,
                              hipStream_t stream) {
    const float* x    = (const float*)d_in[0];
    const float* w    = (const float*)d_in[1];
    const float* bias = (const float*)d_in[2];
    float* out        = (float*)d_out;

    __hip_bfloat16* W2 = (__hip_bfloat16*)d_ws;
    __hip_bfloat16* P  = (__hip_bfloat16*)((char*)d_ws + WEXP2_BYTES);

    wexp2_kernel<<<(WEXP2_ELEMS + 255) / 256, 256, 0, stream>>>(w, W2);
    pad_interior<<<20 * 64 * 2 * 3, 256, 0, stream>>>(x, P);
    pad_border<<<(20 * NBORD * KD + 255) / 256, 256, 0, stream>>>(x, P);
    conv_mfma<<<3840, 256, 0, stream>>>(P, W2, bias, out);
}

// Round 4
// 578.906 us; speedup vs baseline: 8.7957x; 1.0448x over previous
//
#include <hip/hip_runtime.h>
#include <hip/hip_bf16.h>

// Problem constants
#define BB    4
#define CIN_  64
#define RIN_  6
#define CH_   5
#define HH    64
#define WW_   128
#define KD    384
#define MD    384
#define PH    66
#define PW    130
#define PSZ   (PH*PW)

#define NTAP 7
#define WEXP2_ELEMS (NTAP*MD*KD)
#define WEXP2_BYTES (WEXP2_ELEMS*2)
#define NBORD 388

typedef __hip_bfloat16 bf16;
typedef __attribute__((ext_vector_type(8))) short bf16x8;
typedef __attribute__((ext_vector_type(4))) float f32x4;

__device__ const int TMAP[NTAP] = {0,1,3,4,5,7,8};
__device__ const int IDXK[6][9] = {
    {5,4,6,6,0,3,6,1,2},
    {4,3,6,5,0,2,6,6,1},
    {3,2,6,4,0,1,6,5,6},
    {2,1,6,3,0,6,6,4,5},
    {1,6,6,2,0,5,6,3,4},
    {6,5,6,1,0,4,6,2,3},
};

// -------- kernel 1: expand weight -> W2 bf16 [tt=7][m=384][k=384]
__global__ void wexp2_kernel(const float* __restrict__ w, bf16* __restrict__ W2) {
    int e = blockIdx.x * blockDim.x + threadIdx.x;
    if (e >= WEXP2_ELEMS) return;
    int k  = e % KD;
    int m  = (e / KD) % MD;
    int tt = e / (KD * MD);
    int t  = TMAP[tt];
    int co = m / 6, ro = m % 6, ci = k / 6, ri = k % 6;
    int rw = (ri - ro + 6) % 6;
    int s  = IDXK[ro][t];
    W2[e] = __float2bfloat16(w[((co * CIN_ + ci) * RIN_ + rw) * 7 + s]);
}

// -------- kernel 2a: interior pad (transpose to channel-last)
// P layout: [b][c][yy=66][xx=130][k=384] bf16
__global__ __launch_bounds__(256) void pad_interior(const float* __restrict__ x,
                                                    bf16* __restrict__ P) {
    int bid  = blockIdx.x;
    int kblk = bid % 3;
    int xh   = (bid / 3) & 1;
    int y    = (bid / 6) % 64;
    int bc   = bid / 384;
    int c = bc % 5, b = bc / 5;

    int lane = threadIdx.x & 63;
    int wv   = threadIdx.x >> 6;
    int k0   = kblk * 128 + wv * 32;
    int sx   = xh * 64 + lane;
    int xx   = sx + 1;

    bool mask0 = (y == 0 && sx == 127) || (y == 63 && sx == 0);

    const float* src = x + ((((size_t)(b * 384 + k0) * 5 + c) * 64 + y) * 128 + sx);
    unsigned int hbuf[16];
    #pragma unroll
    for (int kk = 0; kk < 32; kk += 2) {
        float v1 = src[(size_t)kk * 40960];
        float v2 = src[(size_t)(kk + 1) * 40960];
        if (mask0) { v1 = 0.f; v2 = 0.f; }
        bf16 h1 = __float2bfloat16(v1);
        bf16 h2 = __float2bfloat16(v2);
        hbuf[kk >> 1] = ((unsigned int)*(unsigned short*)&h2 << 16) |
                        (unsigned int)*(unsigned short*)&h1;
    }
    bf16* dst = P + (((size_t)(b * 5 + c) * PH + (y + 1)) * PW + xx) * KD + k0;
    uint4* d4 = (uint4*)dst;
    #pragma unroll
    for (int q = 0; q < 4; ++q)
        d4[q] = make_uint4(hbuf[4*q], hbuf[4*q+1], hbuf[4*q+2], hbuf[4*q+3]);
}

// -------- kernel 2b: border gather
__global__ void pad_border(const float* __restrict__ x, bf16* __restrict__ P) {
    int e = blockIdx.x * blockDim.x + threadIdx.x;
    if (e >= 20 * NBORD * KD) return;
    int k  = e % KD;
    int p  = (e / KD) % NBORD;
    int bc = e / (KD * NBORD);
    int c = bc % 5, b = bc / 5;
    int yy, xx;
    if (p < 130)      { yy = 0;  xx = p; }
    else if (p < 260) { yy = 65; xx = p - 130; }
    else if (p < 324) { yy = 1 + (p - 260); xx = 0; }
    else              { yy = 1 + (p - 324); xx = 129; }

    int ci = k / RIN_, r = k % RIN_;
    int sr = r, sc = c, sy = 0, sx = 0;
    bool zi = false;
    if (xx == 129) {
        if (yy >= 2) { sr = (r + 5) % 6; sc = (c + 1) % 5; sy = 0; sx = 129 - yy; }
        else zi = true;
    } else if (yy == 0) {
        if (xx >= 1 && xx <= 64)        { sc = (c + 4) % 5; sy = 63; sx = 63 + xx; }
        else if (xx >= 65 && xx <= 128) { sr = (r + 1) % 6; sc = (c + 4) % 5; sy = 128 - xx; sx = 127; }
        else zi = true;
    } else if (yy == 65) {
        if (xx >= 65 && xx <= 128)      { sc = (c + 1) % 5; sy = 0; sx = xx - 65; }
        else if (xx >= 2 && xx <= 64)   { sr = (r + 1) % 6; sc = (c + 1) % 5; sy = 65 - xx; sx = 0; }
        else zi = true;
    } else { // xx==0, yy in [1,64]
        sr = (r + 5) % 6; sc = (c + 4) % 5; sy = 63; sx = 64 - yy;
    }
    if (zi) { sr = 0; sc = 0; sy = 0; sx = 0; }
    float v = x[((((size_t)b * 384 + (ci * 6 + sr)) * 5 + sc) * 64 + sy) * 128 + sx];
    if ((sy == 0 && sx == 127) || (sy == 63 && sx == 0)) v = 0.f;
    P[(((size_t)(b * 5 + c) * PH + yy) * PW + xx) * KD + k] = __float2bfloat16(v);
}

// -------- kernel 3: implicit-GEMM conv, 8-wave 2-phase-per-tile counted-vmcnt schedule
// block: BM=128 m x BN=256 n (2 y-rows x 128 x); 8 waves (2 wm x 4 wn), 64x64 each
// K: 84 tiles = 7 taps x 12 chunks of 32; LDS: 3 buffers (stage t+2 while computing t)
// vmcnt(3) steady state (3 loads/tile/wave in flight), never 0 in main loop
#define DYP 0x2950   // packed dy per tap: 0,0,1,1,1,2,2
#define DXP 0x2644   // packed dx per tap: 0,1,0,1,2,1,2

#define GLD(g, l) __builtin_amdgcn_global_load_lds( \
    (const __attribute__((address_space(1))) void*)(g), \
    (__attribute__((address_space(3))) void*)(l), 16, 0, 0)
#define MFMA_(a, b, c) __builtin_amdgcn_mfma_f32_16x16x32_bf16((a), (b), (c), 0, 0, 0)

__global__ __launch_bounds__(512) void conv_mfma8(
        const bf16* __restrict__ P, const bf16* __restrict__ W2,
        const float* __restrict__ bias, float* __restrict__ out) {
    __shared__ __align__(16) bf16 As[3][4096];   // 128 m  x 32 k per buf (8 KB)
    __shared__ __align__(16) bf16 Bs[3][8192];   // 256 n  x 32 k per buf (16 KB)

    const int bid = blockIdx.x;
    const int w   = (bid & 7) * 240 + (bid >> 3);   // XCD swizzle, 1920 = 8*240
    const int mblk  = w % 3;
    const int ntile = (w / 3) % 32;
    const int bc    = w / 96;
    const int c = bc % 5, b = bc / 5;
    const int y0 = ntile * 2;

    const int tid  = threadIdx.x;
    const int lane = tid & 63;
    const int wv   = tid >> 6;
    const int wm   = wv >> 2, wn = wv & 3;
    const int lm   = lane & 15, lg = lane >> 4;

    const bf16* Pslice = P + (size_t)(b * 5 + c) * PSZ * KD;

    // staging thread-constants (pre-swizzled global source, linear LDS dest)
    const int rA  = tid >> 2;                       // m-row (A) / x-col (B), 0..127
    const int kg  = (tid & 3) ^ ((rA >> 1) & 3);    // swizzled k-group
    const bf16* gA0 = W2 + (size_t)(mblk * 128 + rA) * KD + kg * 8;
    const bf16* gB0 = Pslice + (size_t)rA * KD + kg * 8;

    // ds-read byte offsets (swizzled): slot = idx*4 + (lg ^ ((idx>>1)&3)), 16 B/slot
    int oA[4], oB[4];
    #pragma unroll
    for (int i = 0; i < 4; ++i) {
        int mm = wm * 64 + i * 16 + lm;
        oA[i] = (mm * 4 + (lg ^ ((mm >> 1) & 3))) * 16;
        int nn = wn * 64 + i * 16 + lm;
        oB[i] = (nn * 4 + (lg ^ ((nn >> 1) & 3))) * 16;
    }
    const char* Ab = (const char*)&As[0][0];
    const char* Bb = (const char*)&Bs[0][0];

    f32x4 acc[4][4] = {};

    // prologue: stage tile 0 -> buf0, tile 1 -> buf1 (tap 0: dy=0, dx=0)
    #pragma unroll
    for (int t = 0; t < 2; ++t) {
        const bf16* ga = gA0 + t * 32;
        const bf16* gb = gB0 + (size_t)y0 * PW * KD + t * 32;
        GLD(ga, &As[t][wv * 512]);
        GLD(gb, &Bs[t][wv * 512]);
        GLD(gb + (size_t)PW * KD, &Bs[t][4096 + wv * 512]);
    }
    asm volatile("s_waitcnt vmcnt(3)" ::: "memory");   // tile 0 landed
    __builtin_amdgcn_s_barrier();

    #pragma unroll 1
    for (int tt = 0; tt < 7; ++tt) {
        #pragma unroll
        for (int kc = 0; kc < 12; ++kc) {
            const int rb   = kc % 3;            // read buffer (static)
            const int sb   = (kc + 2) % 3;      // stage buffer (static)
            const int skc  = (kc + 2) % 12;     // staged tile k-chunk (static)
            const int stt  = tt + (kc + 2) / 12;
            const bool dostage = (stt < 7);

            // ---- phase 0: ds_read a0..a3, b0, b1; stage A + B-unit0 of tile t+2
            bf16x8 a0 = *(const bf16x8*)(Ab + rb * 8192 + oA[0]);
            bf16x8 a1 = *(const bf16x8*)(Ab + rb * 8192 + oA[1]);
            bf16x8 a2 = *(const bf16x8*)(Ab + rb * 8192 + oA[2]);
            bf16x8 a3 = *(const bf16x8*)(Ab + rb * 8192 + oA[3]);
            bf16x8 b0 = *(const bf16x8*)(Bb + rb * 16384 + oB[0]);
            bf16x8 b1 = *(const bf16x8*)(Bb + rb * 16384 + oB[1]);

            const bf16* gb = nullptr;
            if (dostage) {
                const int dy = (DYP >> (2 * stt)) & 3;
                const int dx = (DXP >> (2 * stt)) & 3;
                const bf16* ga = gA0 + (size_t)stt * (MD * KD) + skc * 32;
                gb = gB0 + ((size_t)(y0 + dy) * PW + dx) * KD + skc * 32;
                GLD(ga, &As[sb][wv * 512]);
                GLD(gb, &Bs[sb][wv * 512]);
            }
            __builtin_amdgcn_s_barrier();
            asm volatile("s_waitcnt lgkmcnt(0)" ::: "memory");
            __builtin_amdgcn_s_setprio(1);
            acc[0][0] = MFMA_(a0, b0, acc[0][0]);
            acc[1][0] = MFMA_(a1, b0, acc[1][0]);
            acc[2][0] = MFMA_(a2, b0, acc[2][0]);
            acc[3][0] = MFMA_(a3, b0, acc[3][0]);
            acc[0][1] = MFMA_(a0, b1, acc[0][1]);
            acc[1][1] = MFMA_(a1, b1, acc[1][1]);
            acc[2][1] = MFMA_(a2, b1, acc[2][1]);
            acc[3][1] = MFMA_(a3, b1, acc[3][1]);
            __builtin_amdgcn_s_setprio(0);
            __builtin_amdgcn_s_barrier();

            // ---- phase 1: ds_read b2, b3; stage B-unit1 of tile t+2
            bf16x8 b2 = *(const bf16x8*)(Bb + rb * 16384 + oB[2]);
            bf16x8 b3 = *(const bf16x8*)(Bb + rb * 16384 + oB[3]);
            if (dostage) GLD(gb + (size_t)PW * KD, &Bs[sb][4096 + wv * 512]);
            __builtin_amdgcn_s_barrier();
            asm volatile("s_waitcnt lgkmcnt(0)" ::: "memory");
            __builtin_amdgcn_s_setprio(1);
            acc[0][2] = MFMA_(a0, b2, acc[0][2]);
            acc[1][2] = MFMA_(a1, b2, acc[1][2]);
            acc[2][2] = MFMA_(a2, b2, acc[2][2]);
            acc[3][2] = MFMA_(a3, b2, acc[3][2]);
            acc[0][3] = MFMA_(a0, b3, acc[0][3]);
            acc[1][3] = MFMA_(a1, b3, acc[1][3]);
            acc[2][3] = MFMA_(a2, b3, acc[2][3]);
            acc[3][3] = MFMA_(a3, b3, acc[3][3]);
            __builtin_amdgcn_s_setprio(0);
            // once-per-tile wait: next tile's data must be landed after this barrier.
            // steady state: 3 newest loads (tile t+2's) may stay in flight.
            if (tt == 6 && kc >= 10) {
                asm volatile("s_waitcnt vmcnt(0)" ::: "memory");
            } else {
                asm volatile("s_waitcnt vmcnt(3)" ::: "memory");
            }
            __builtin_amdgcn_s_barrier();
        }
    }

    // epilogue: bias + VMASK + store
    const int m0 = mblk * 128 + wm * 64;
    const int yq = y0 + (wn >> 1);
    const int xb = (wn & 1) * 64;
    #pragma unroll
    for (int i = 0; i < 4; ++i) {
        #pragma unroll
        for (int r = 0; r < 4; ++r) {
            int m = m0 + i * 16 + lg * 4 + r;
            float bv = bias[m / 6];
            #pragma unroll
            for (int j = 0; j < 4; ++j) {
                int xq = xb + j * 16 + lm;
                float v = acc[i][j][r] + bv;
                if ((yq == 0 && xq == 127) || (yq == 63 && xq == 0)) v = 0.f;
                out[((size_t)(b * MD + m) * CH_ + c) * (HH * WW_) + yq * WW_ + xq] = v;
            }
        }
    }
}

extern "C" void kernel_launch(void* const* d_in, const int* in_sizes, int n_in,
                              void* d_out, int out_size, void* d_ws, size_t ws_size,
                              hipStream_t stream) {
    const float* x    = (const float*)d_in[0];
    const float* w    = (const float*)d_in[1];
    const float* bias = (const float*)d_in[2];
    float* out        = (float*)d_out;

    bf16* W2 = (bf16*)d_ws;
    bf16* P  = (bf16*)((char*)d_ws + WEXP2_BYTES);

    wexp2_kernel<<<(WEXP2_ELEMS + 255) / 256, 256, 0, stream>>>(w, W2);
    pad_interior<<<20 * 64 * 2 * 3, 256, 0, stream>>>(x, P);
    pad_border<<<(20 * NBORD * KD + 255) / 256, 256, 0, stream>>>(x, P);

    // grid: 3 m-blocks x 32 n-tiles x 20 (b,c) = 1920 blocks, 512 threads
    conv_mfma8<<<1920, 512, 0, stream>>>(P, W2, bias, out);
}

// Round 6
// 507.419 us; speedup vs baseline: 10.0349x; 1.1409x over previous
//
#include <hip/hip_runtime.h>
#include <hip/hip_bf16.h>

// Problem constants
#define BB    4
#define CIN_  64
#define RIN_  6
#define CH_   5
#define HH    64
#define WW_   128
#define KD    384
#define MD    384
#define PH    66
#define PW    130
#define PSZ   (PH*PW)

#define NTAP 7
#define WEXP2_ELEMS (NTAP*MD*KD)
#define WEXP2_BYTES (WEXP2_ELEMS*2)
#define NBORD 388

typedef __hip_bfloat16 bf16;
typedef __attribute__((ext_vector_type(8))) short bf16x8;
typedef __attribute__((ext_vector_type(4))) float f32x4;

__device__ const int TMAP[NTAP] = {0,1,3,4,5,7,8};
__device__ const int IDXK[6][9] = {
    {5,4,6,6,0,3,6,1,2},
    {4,3,6,5,0,2,6,6,1},
    {3,2,6,4,0,1,6,5,6},
    {2,1,6,3,0,6,6,4,5},
    {1,6,6,2,0,5,6,3,4},
    {6,5,6,1,0,4,6,2,3},
};

// -------- kernel 1: expand weight -> W2 bf16 [tt=7][m=384][k=384]
__global__ void wexp2_kernel(const float* __restrict__ w, bf16* __restrict__ W2) {
    int e = blockIdx.x * blockDim.x + threadIdx.x;
    if (e >= WEXP2_ELEMS) return;
    int k  = e % KD;
    int m  = (e / KD) % MD;
    int tt = e / (KD * MD);
    int t  = TMAP[tt];
    int co = m / 6, ro = m % 6, ci = k / 6, ri = k % 6;
    int rw = (ri - ro + 6) % 6;
    int s  = IDXK[ro][t];
    W2[e] = __float2bfloat16(w[((co * CIN_ + ci) * RIN_ + rw) * 7 + s]);
}

// -------- kernel 2a: interior pad (transpose to channel-last)
// P layout: [b][c][yy=66][xx=130][k=384] bf16
__global__ __launch_bounds__(256) void pad_interior(const float* __restrict__ x,
                                                    bf16* __restrict__ P) {
    int bid  = blockIdx.x;
    int kblk = bid % 3;
    int xh   = (bid / 3) & 1;
    int y    = (bid / 6) % 64;
    int bc   = bid / 384;
    int c = bc % 5, b = bc / 5;

    int lane = threadIdx.x & 63;
    int wv   = threadIdx.x >> 6;
    int k0   = kblk * 128 + wv * 32;
    int sx   = xh * 64 + lane;
    int xx   = sx + 1;

    bool mask0 = (y == 0 && sx == 127) || (y == 63 && sx == 0);

    const float* src = x + ((((size_t)(b * 384 + k0) * 5 + c) * 64 + y) * 128 + sx);
    unsigned int hbuf[16];
    #pragma unroll
    for (int kk = 0; kk < 32; kk += 2) {
        float v1 = src[(size_t)kk * 40960];
        float v2 = src[(size_t)(kk + 1) * 40960];
        if (mask0) { v1 = 0.f; v2 = 0.f; }
        bf16 h1 = __float2bfloat16(v1);
        bf16 h2 = __float2bfloat16(v2);
        hbuf[kk >> 1] = ((unsigned int)*(unsigned short*)&h2 << 16) |
                        (unsigned int)*(unsigned short*)&h1;
    }
    bf16* dst = P + (((size_t)(b * 5 + c) * PH + (y + 1)) * PW + xx) * KD + k0;
    uint4* d4 = (uint4*)dst;
    #pragma unroll
    for (int q = 0; q < 4; ++q)
        d4[q] = make_uint4(hbuf[4*q], hbuf[4*q+1], hbuf[4*q+2], hbuf[4*q+3]);
}

// -------- kernel 2b: border gather
__global__ void pad_border(const float* __restrict__ x, bf16* __restrict__ P) {
    int e = blockIdx.x * blockDim.x + threadIdx.x;
    if (e >= 20 * NBORD * KD) return;
    int k  = e % KD;
    int p  = (e / KD) % NBORD;
    int bc = e / (KD * NBORD);
    int c = bc % 5, b = bc / 5;
    int yy, xx;
    if (p < 130)      { yy = 0;  xx = p; }
    else if (p < 260) { yy = 65; xx = p - 130; }
    else if (p < 324) { yy = 1 + (p - 260); xx = 0; }
    else              { yy = 1 + (p - 324); xx = 129; }

    int ci = k / RIN_, r = k % RIN_;
    int sr = r, sc = c, sy = 0, sx = 0;
    bool zi = false;
    if (xx == 129) {
        if (yy >= 2) { sr = (r + 5) % 6; sc = (c + 1) % 5; sy = 0; sx = 129 - yy; }
        else zi = true;
    } else if (yy == 0) {
        if (xx >= 1 && xx <= 64)        { sc = (c + 4) % 5; sy = 63; sx = 63 + xx; }
        else if (xx >= 65 && xx <= 128) { sr = (r + 1) % 6; sc = (c + 4) % 5; sy = 128 - xx; sx = 127; }
        else zi = true;
    } else if (yy == 65) {
        if (xx >= 65 && xx <= 128)      { sc = (c + 1) % 5; sy = 0; sx = xx - 65; }
        else if (xx >= 2 && xx <= 64)   { sr = (r + 1) % 6; sc = (c + 1) % 5; sy = 65 - xx; sx = 0; }
        else zi = true;
    } else { // xx==0, yy in [1,64]
        sr = (r + 5) % 6; sc = (c + 4) % 5; sy = 63; sx = 64 - yy;
    }
    if (zi) { sr = 0; sc = 0; sy = 0; sx = 0; }
    float v = x[((((size_t)b * 384 + (ci * 6 + sr)) * 5 + sc) * 64 + sy) * 128 + sx];
    if ((sy == 0 && sx == 127) || (sy == 63 && sx == 0)) v = 0.f;
    P[(((size_t)(b * 5 + c) * PH + yy) * PW + xx) * KD + k] = __float2bfloat16(v);
}

// -------- kernel 3: implicit-GEMM conv
// 4 waves/block (256 thr); wave-tile 128m x 64n (acc 8x4 frags)
// BM=128, BN=256 (2 y-rows x 128 x), BK=32; 84 K-tiles = 7 taps x 12 chunks
// LDS: 3 buffers (stage t+2 while computing t); vmcnt(6) steady state
#define DYP 0x2950   // packed dy per tap: 0,0,1,1,1,2,2
#define DXP 0x2644   // packed dx per tap: 0,1,0,1,2,1,2

#define GLD(g, l) __builtin_amdgcn_global_load_lds( \
    (const __attribute__((address_space(1))) void*)(g), \
    (__attribute__((address_space(3))) void*)(l), 16, 0, 0)
#define MFMA_(a, b, c) __builtin_amdgcn_mfma_f32_16x16x32_bf16((a), (b), (c), 0, 0, 0)

__global__ __launch_bounds__(256, 2) void conv_mfma4(
        const bf16* __restrict__ P, const bf16* __restrict__ W2,
        const float* __restrict__ bias, float* __restrict__ out) {
    __shared__ __align__(16) bf16 As[3][4096];   // 128 m x 32 k per buf (8 KB)
    __shared__ __align__(16) bf16 Bs[3][8192];   // 256 n x 32 k per buf (16 KB)

    const int bid = blockIdx.x;
    const int w   = (bid & 7) * 240 + (bid >> 3);   // XCD swizzle, 1920 = 8*240
    const int mblk  = w % 3;
    const int ntile = (w / 3) % 32;
    const int bc    = w / 96;
    const int c = bc % 5, b = bc / 5;
    const int y0 = ntile * 2;

    const int tid  = threadIdx.x;
    const int lane = tid & 63;
    const int wv   = tid >> 6;          // 0..3
    const int lm   = lane & 15, lg = lane >> 4;

    const bf16* Pslice = P + (size_t)(b * 5 + c) * PSZ * KD;

    // ds-read byte offsets (swizzled): slot = idx*4 + (lg ^ ((idx>>1)&3)), 16 B/slot
    int oA[8], oB[4];
    #pragma unroll
    for (int i = 0; i < 8; ++i) {
        int mm = i * 16 + lm;
        oA[i] = (mm * 4 + (lg ^ ((mm >> 1) & 3))) * 16;
    }
    #pragma unroll
    for (int j = 0; j < 4; ++j) {
        int nn = wv * 64 + j * 16 + lm;
        oB[j] = (nn * 4 + (lg ^ ((nn >> 1) & 3))) * 16;
    }
    const char* Ab = (const char*)&As[0][0];
    const char* Bb = (const char*)&Bs[0][0];

    // staging thread-constant base pointers (pre-swizzled global source)
    const bf16* gA[2];
    #pragma unroll
    for (int q = 0; q < 2; ++q) {
        int s = wv * 128 + q * 64 + lane;
        int row = s >> 2, j = s & 3;
        gA[q] = W2 + (size_t)(mblk * 128 + row) * KD + ((j ^ ((row >> 1) & 3)) << 3);
    }
    // B: LDS col n maps to padded image as: row (y0+dy) + (n>>7), x = dx + (n&127).
    // Fold the row split into the base: ncol = (col&127) + (col>>7)*PW.
    // (Round-5 bug: used col directly, so cols 128..255 wrapped into the wrong
    //  row at the wrong x offset.)
    const bf16* gB[4];
    #pragma unroll
    for (int q = 0; q < 4; ++q) {
        int s = wv * 256 + q * 64 + lane;
        int col = s >> 2, j = s & 3;
        int ncol = (col & 127) + (col >> 7) * PW;
        gB[q] = Pslice + (size_t)ncol * KD + ((j ^ ((col >> 1) & 3)) << 3);
    }

    f32x4 acc[8][4] = {};

    // prologue: stage tile 0 -> buf0, tile 1 -> buf1 (tap 0: dy=0, dx=0)
    #pragma unroll
    for (int t = 0; t < 2; ++t) {
        size_t offA = (size_t)t * 32;
        size_t offB = (size_t)y0 * PW * KD + t * 32;
        GLD(gA[0] + offA, &As[t][(wv * 128) * 8]);
        GLD(gA[1] + offA, &As[t][(wv * 128 + 64) * 8]);
        #pragma unroll
        for (int q = 0; q < 4; ++q)
            GLD(gB[q] + offB, &Bs[t][(wv * 256 + q * 64) * 8]);
    }
    asm volatile("s_waitcnt vmcnt(6)" ::: "memory");   // tile 0 landed
    __builtin_amdgcn_s_barrier();

    #pragma unroll 1
    for (int tt = 0; tt < 7; ++tt) {
        #pragma unroll
        for (int kc = 0; kc < 12; ++kc) {
            const int rb   = kc % 3;            // read buffer (static)
            const int sb   = (kc + 2) % 3;      // stage buffer (static)
            const int skc  = (kc + 2) % 12;     // staged tile k-chunk (static)
            const int stt  = tt + (kc + 2) / 12;
            const bool dostage = (stt < 7);

            // ---- phase 0: ds_read a0..a7, b0, b1; stage A + half of B of tile t+2
            bf16x8 a0 = *(const bf16x8*)(Ab + rb * 8192 + oA[0]);
            bf16x8 a1 = *(const bf16x8*)(Ab + rb * 8192 + oA[1]);
            bf16x8 a2 = *(const bf16x8*)(Ab + rb * 8192 + oA[2]);
            bf16x8 a3 = *(const bf16x8*)(Ab + rb * 8192 + oA[3]);
            bf16x8 a4 = *(const bf16x8*)(Ab + rb * 8192 + oA[4]);
            bf16x8 a5 = *(const bf16x8*)(Ab + rb * 8192 + oA[5]);
            bf16x8 a6 = *(const bf16x8*)(Ab + rb * 8192 + oA[6]);
            bf16x8 a7 = *(const bf16x8*)(Ab + rb * 8192 + oA[7]);
            bf16x8 b0 = *(const bf16x8*)(Bb + rb * 16384 + oB[0]);
            bf16x8 b1 = *(const bf16x8*)(Bb + rb * 16384 + oB[1]);

            size_t offA = 0, offB = 0;
            if (dostage) {
                const int dy = (DYP >> (2 * stt)) & 3;
                const int dx = (DXP >> (2 * stt)) & 3;
                offA = (size_t)stt * (MD * KD) + skc * 32;
                offB = ((size_t)(y0 + dy) * PW + dx) * KD + skc * 32;
                GLD(gA[0] + offA, &As[sb][(wv * 128) * 8]);
                GLD(gA[1] + offA, &As[sb][(wv * 128 + 64) * 8]);
                GLD(gB[0] + offB, &Bs[sb][(wv * 256) * 8]);
                GLD(gB[1] + offB, &Bs[sb][(wv * 256 + 64) * 8]);
            }
            __builtin_amdgcn_s_barrier();
            asm volatile("s_waitcnt lgkmcnt(0)" ::: "memory");
            __builtin_amdgcn_s_setprio(1);
            acc[0][0] = MFMA_(a0, b0, acc[0][0]);
            acc[1][0] = MFMA_(a1, b0, acc[1][0]);
            acc[2][0] = MFMA_(a2, b0, acc[2][0]);
            acc[3][0] = MFMA_(a3, b0, acc[3][0]);
            acc[4][0] = MFMA_(a4, b0, acc[4][0]);
            acc[5][0] = MFMA_(a5, b0, acc[5][0]);
            acc[6][0] = MFMA_(a6, b0, acc[6][0]);
            acc[7][0] = MFMA_(a7, b0, acc[7][0]);
            acc[0][1] = MFMA_(a0, b1, acc[0][1]);
            acc[1][1] = MFMA_(a1, b1, acc[1][1]);
            acc[2][1] = MFMA_(a2, b1, acc[2][1]);
            acc[3][1] = MFMA_(a3, b1, acc[3][1]);
            acc[4][1] = MFMA_(a4, b1, acc[4][1]);
            acc[5][1] = MFMA_(a5, b1, acc[5][1]);
            acc[6][1] = MFMA_(a6, b1, acc[6][1]);
            acc[7][1] = MFMA_(a7, b1, acc[7][1]);
            __builtin_amdgcn_s_setprio(0);
            __builtin_amdgcn_s_barrier();

            // ---- phase 1: ds_read b2, b3; stage other half of B of tile t+2
            bf16x8 b2 = *(const bf16x8*)(Bb + rb * 16384 + oB[2]);
            bf16x8 b3 = *(const bf16x8*)(Bb + rb * 16384 + oB[3]);
            if (dostage) {
                GLD(gB[2] + offB, &Bs[sb][(wv * 256 + 128) * 8]);
                GLD(gB[3] + offB, &Bs[sb][(wv * 256 + 192) * 8]);
            }
            __builtin_amdgcn_s_barrier();
            asm volatile("s_waitcnt lgkmcnt(0)" ::: "memory");
            __builtin_amdgcn_s_setprio(1);
            acc[0][2] = MFMA_(a0, b2, acc[0][2]);
            acc[1][2] = MFMA_(a1, b2, acc[1][2]);
            acc[2][2] = MFMA_(a2, b2, acc[2][2]);
            acc[3][2] = MFMA_(a3, b2, acc[3][2]);
            acc[4][2] = MFMA_(a4, b2, acc[4][2]);
            acc[5][2] = MFMA_(a5, b2, acc[5][2]);
            acc[6][2] = MFMA_(a6, b2, acc[6][2]);
            acc[7][2] = MFMA_(a7, b2, acc[7][2]);
            acc[0][3] = MFMA_(a0, b3, acc[0][3]);
            acc[1][3] = MFMA_(a1, b3, acc[1][3]);
            acc[2][3] = MFMA_(a2, b3, acc[2][3]);
            acc[3][3] = MFMA_(a3, b3, acc[3][3]);
            acc[4][3] = MFMA_(a4, b3, acc[4][3]);
            acc[5][3] = MFMA_(a5, b3, acc[5][3]);
            acc[6][3] = MFMA_(a6, b3, acc[6][3]);
            acc[7][3] = MFMA_(a7, b3, acc[7][3]);
            __builtin_amdgcn_s_setprio(0);
            // once-per-tile wait: tile t+1 must be landed after this barrier.
            // steady state: current chunk's 6 loads (tile t+2) stay in flight.
            if (tt == 6 && kc >= 10) {
                asm volatile("s_waitcnt vmcnt(0)" ::: "memory");
            } else {
                asm volatile("s_waitcnt vmcnt(6)" ::: "memory");
            }
            __builtin_amdgcn_s_barrier();
        }
    }

    // epilogue: bias + VMASK + store
    const int m0 = mblk * 128;
    const int yq = y0 + (wv >> 1);
    const int xb = (wv & 1) * 64;
    #pragma unroll
    for (int i = 0; i < 8; ++i) {
        #pragma unroll
        for (int r = 0; r < 4; ++r) {
            int m = m0 + i * 16 + lg * 4 + r;
            float bv = bias[m / 6];
            #pragma unroll
            for (int j = 0; j < 4; ++j) {
                int xq = xb + j * 16 + lm;
                float v = acc[i][j][r] + bv;
                if ((yq == 0 && xq == 127) || (yq == 63 && xq == 0)) v = 0.f;
                out[((size_t)(b * MD + m) * CH_ + c) * (HH * WW_) + yq * WW_ + xq] = v;
            }
        }
    }
}

extern "C" void kernel_launch(void* const* d_in, const int* in_sizes, int n_in,
                              void* d_out, int out_size, void* d_ws, size_t ws_size,
                              hipStream_t stream) {
    const float* x    = (const float*)d_in[0];
    const float* w    = (const float*)d_in[1];
    const float* bias = (const float*)d_in[2];
    float* out        = (float*)d_out;

    bf16* W2 = (bf16*)d_ws;
    bf16* P  = (bf16*)((char*)d_ws + WEXP2_BYTES);

    wexp2_kernel<<<(WEXP2_ELEMS + 255) / 256, 256, 0, stream>>>(w, W2);
    pad_interior<<<20 * 64 * 2 * 3, 256, 0, stream>>>(x, P);
    pad_border<<<(20 * NBORD * KD + 255) / 256, 256, 0, stream>>>(x, P);

    // grid: 3 m-blocks x 32 n-tiles x 20 (b,c) = 1920 blocks, 256 threads
    conv_mfma4<<<1920, 256, 0, stream>>>(P, W2, bias, out);
}